// Round 4
// baseline (69.589 us; speedup 1.0000x reference)
//
#include <hip/hip_runtime.h>

// GeneralPulling, two-phase:
//   Kernel A: dist[i][j] = clip(sqrt(clip(|e_i|^2+|r_j|^2-2 e_i.r_j, 0)), 1e-6)
//             (tiled f32 GEMM-style, 64x64 tile per block, K=128 staged in LDS)
//   Kernel B: per t: D_ap=dist[anc,pos], D_an=dist[anc,neg];
//             lam = edge[anc,neg,:]*exp(-1/x); r = ratio + lam*(1-ratio);
//             z = emb[anc] + r*(ref[neg]-emb[anc]);
//             out[t] = (D_ap>=D_an) ? ref[neg] : z
// Fallback single fused kernel if ws_size too small.

typedef __attribute__((ext_vector_type(4))) float float4_t;

#define NB  128   // NBITS
#define AM  64
#define AN  64
#define UT  4     // t's per 32-lane group in kernel B

// ---------------- Kernel A: distance matrix ----------------
__global__ __launch_bounds__(256) void dist_kernel(
    const float* __restrict__ emb,   // [B,128]
    const float* __restrict__ refe,  // [B,128]
    float*       __restrict__ dist,  // [B,B]
    int B)
{
    __shared__ float As[AM][NB + 1];   // +1 pad: conflict-free column reads
    __shared__ float Bs[AN][NB + 1];

    const int i0  = blockIdx.x * AM;
    const int j0  = blockIdx.y * AN;
    const int tid = threadIdx.x;

    // Cooperative stage: 64 rows x 128 cols each, coalesced float4 loads.
    #pragma unroll
    for (int q = 0; q < 8; ++q) {
        const int idx = tid + q * 256;        // 0..2047
        const int row = idx >> 5;
        const int c4  = (idx & 31) << 2;
        const float4_t a = *(const float4_t*)(emb  + (size_t)(i0 + row) * NB + c4);
        const float4_t b = *(const float4_t*)(refe + (size_t)(j0 + row) * NB + c4);
        #pragma unroll
        for (int k = 0; k < 4; ++k) { As[row][c4 + k] = a[k]; Bs[row][c4 + k] = b[k]; }
    }
    __syncthreads();

    const int tx = tid & 15;       // j sub-tile
    const int ty = tid >> 4;       // i sub-tile
    float s[4][4] = {{0.f}};
    float na[4] = {0.f}, nbb[4] = {0.f};

    for (int k = 0; k < NB; ++k) {
        float a[4], b[4];
        #pragma unroll
        for (int m = 0; m < 4; ++m) a[m] = As[ty * 4 + m][k];
        #pragma unroll
        for (int n = 0; n < 4; ++n) b[n] = Bs[tx * 4 + n][k];
        #pragma unroll
        for (int m = 0; m < 4; ++m) na[m] += a[m] * a[m];
        #pragma unroll
        for (int n = 0; n < 4; ++n) nbb[n] += b[n] * b[n];
        #pragma unroll
        for (int m = 0; m < 4; ++m)
            #pragma unroll
            for (int n = 0; n < 4; ++n) s[m][n] += a[m] * b[n];
    }

    #pragma unroll
    for (int m = 0; m < 4; ++m) {
        float4_t o;
        #pragma unroll
        for (int n = 0; n < 4; ++n) {
            const float sq = na[m] + nbb[n] - 2.0f * s[m][n];
            o[n] = fmaxf(sqrtf(fmaxf(sq, 0.0f)), 1e-6f);
        }
        *(float4_t*)(dist + (size_t)(i0 + ty * 4 + m) * B + j0 + tx * 4) = o;
    }
}

// ---------------- Kernel B: streaming pull ----------------
__global__ __launch_bounds__(256) void pull_kernel(
    const float* __restrict__ emb,
    const float* __restrict__ refe,
    const int*   __restrict__ anc_idx,
    const int*   __restrict__ pos_idx,
    const int*   __restrict__ neg_idx,
    const float* __restrict__ edge,    // [B,B,128]
    const float* __restrict__ javg_p,  // [1]
    const float* __restrict__ dist,    // [B,B]
    float*       __restrict__ out,     // [T,128]
    int T, int B)
{
    const int tid   = threadIdx.x;
    const int g     = tid >> 5;
    const int sub   = tid & 31;
    const int tbase = (blockIdx.x * 8 + g) * UT;

    int anc[UT], pos[UT], neg[UT];
    #pragma unroll
    for (int u = 0; u < UT; ++u) {
        const int t = min(tbase + u, T - 1);   // clamp; store is guarded below
        anc[u] = anc_idx[t];
        pos[u] = pos_idx[t];
        neg[u] = neg_idx[t];
    }

    // Issue all streaming edge gathers first (maximize MLP).
    float4_t le[UT];
    #pragma unroll
    for (int u = 0; u < UT; ++u)
        le[u] = *(const float4_t*)(edge + ((size_t)anc[u] * B + neg[u]) * NB + sub * 4);

    // L2/L3-resident scalar distance loads (uniform per group -> broadcast).
    float dap[UT], dan[UT];
    #pragma unroll
    for (int u = 0; u < UT; ++u) {
        dap[u] = dist[(size_t)anc[u] * B + pos[u]];
        dan[u] = dist[(size_t)anc[u] * B + neg[u]];
    }

    // L2-resident table rows.
    float4_t ea[UT], rn[UT];
    #pragma unroll
    for (int u = 0; u < UT; ++u) {
        ea[u] = *(const float4_t*)(emb  + (size_t)anc[u] * NB + sub * 4);
        rn[u] = *(const float4_t*)(refe + (size_t)neg[u] * NB + sub * 4);
    }

    const float javg  = javg_p[0];
    const float x     = (javg == 0.0f) ? 1e6f : javg;
    const float scale = expf(-1.0f / x);

    #pragma unroll
    for (int u = 0; u < UT; ++u) {
        const bool  negmask = (dap[u] >= dan[u]);
        const float ratio   = dap[u] / dan[u];
        float4_t o;
        #pragma unroll
        for (int k = 0; k < 4; ++k) {
            const float lam = le[u][k] * scale;
            const float r   = ratio + lam * (1.0f - ratio);
            const float z   = ea[u][k] + r * (rn[u][k] - ea[u][k]);
            o[k] = negmask ? rn[u][k] : z;
        }
        const int t = tbase + u;
        if (t < T)
            __builtin_nontemporal_store(o, (float4_t*)(out + (size_t)t * NB + sub * 4));
    }
}

// ---------------- Fallback fused kernel (round-2, known-good) ----------------
__global__ __launch_bounds__(256) void fused_kernel(
    const float* __restrict__ emb, const float* __restrict__ refe,
    const int* __restrict__ anc_idx, const int* __restrict__ pos_idx,
    const int* __restrict__ neg_idx, const float* __restrict__ edge,
    const float* __restrict__ javg_p, float* __restrict__ out, int T, int B)
{
    const int tid = threadIdx.x;
    const int g   = tid >> 5;
    const int sub = tid & 31;
    const int t   = blockIdx.x * 8 + g;
    if (t >= T) return;

    const int anc = anc_idx[t], pos = pos_idx[t], neg = neg_idx[t];
    const float4_t le = *(const float4_t*)(edge + ((size_t)anc * B + neg) * NB + sub * 4);
    const float4_t ea = *(const float4_t*)(emb  + (size_t)anc * NB + sub * 4);
    const float4_t rp = *(const float4_t*)(refe + (size_t)pos * NB + sub * 4);
    const float4_t rn = *(const float4_t*)(refe + (size_t)neg * NB + sub * 4);

    const float javg  = javg_p[0];
    const float x     = (javg == 0.0f) ? 1e6f : javg;
    const float scale = expf(-1.0f / x);

    float sap = 0.0f, san = 0.0f;
    #pragma unroll
    for (int k = 0; k < 4; ++k) {
        const float dp = ea[k] - rp[k];
        const float dn = ea[k] - rn[k];
        sap += dp * dp; san += dn * dn;
    }
    #pragma unroll
    for (int m = 1; m < 32; m <<= 1) {
        sap += __shfl_xor(sap, m, 64);
        san += __shfl_xor(san, m, 64);
    }

    const float D_ap = fmaxf(sqrtf(fmaxf(sap, 0.0f)), 1e-6f);
    const float D_an = fmaxf(sqrtf(fmaxf(san, 0.0f)), 1e-6f);
    const bool  negmask = (D_ap >= D_an);
    const float ratio   = D_ap / D_an;

    float4_t o;
    #pragma unroll
    for (int k = 0; k < 4; ++k) {
        const float lam = le[k] * scale;
        const float r   = ratio + lam * (1.0f - ratio);
        const float z   = ea[k] + r * (rn[k] - ea[k]);
        o[k] = negmask ? rn[k] : z;
    }
    *(float4_t*)(out + (size_t)t * NB + sub * 4) = o;
}

extern "C" void kernel_launch(void* const* d_in, const int* in_sizes, int n_in,
                              void* d_out, int out_size, void* d_ws, size_t ws_size,
                              hipStream_t stream) {
    const float* emb  = (const float*)d_in[0];
    const float* refe = (const float*)d_in[1];
    const int*   anc  = (const int*)d_in[2];
    const int*   pos  = (const int*)d_in[3];
    const int*   neg  = (const int*)d_in[4];
    const float* edge = (const float*)d_in[5];
    const float* javg = (const float*)d_in[6];
    float*       out  = (float*)d_out;

    const int T = in_sizes[2];        // 262144
    const int B = in_sizes[0] / NB;   // 1024

    const size_t need = (size_t)B * (size_t)B * sizeof(float);
    if (ws_size >= need && (B % 64) == 0) {
        float* dist = (float*)d_ws;
        dim3 gridA(B / AM, B / AN);
        dist_kernel<<<gridA, 256, 0, stream>>>(emb, refe, dist, B);
        const int tpb = 8 * UT;  // 32 t's per block
        pull_kernel<<<(T + tpb - 1) / tpb, 256, 0, stream>>>(
            emb, refe, anc, pos, neg, edge, javg, dist, out, T, B);
    } else {
        fused_kernel<<<(T + 7) / 8, 256, 0, stream>>>(
            emb, refe, anc, pos, neg, edge, javg, out, T, B);
    }
}

// Round 5
// 67.501 us; speedup vs baseline: 1.0309x; 1.0309x over previous
//
#include <hip/hip_runtime.h>

// GeneralPulling (all f32), fused, round-3 structure + nontemporal streaming:
//   D_ap = ||emb[anc]-ref[pos]||, D_an = ||emb[anc]-ref[neg]||  (clip >= 1e-6)
//   lam_eta = edge[anc,neg,:] * exp(-1/J_avg)   (J_avg==0 -> x=1e6)
//   r = (1-lam_eta)*(D_ap/D_an) + lam_eta
//   z_hat = (D_ap >= D_an) ? ref[neg] : (1-r)*emb[anc] + r*ref[neg]
//
// 32 lanes per t, one float4 per lane -> 512 B coalesced row accesses.
// 2 t's per thread. Edge gather + output store are NONTEMPORAL (single-use
// streams; avoid L2/L3 allocate+evict churn). Table reads stay cached.

typedef __attribute__((ext_vector_type(4))) float float4_t;

#define NB  128   // NBITS
#define TPB 16    // t's per block (8 groups x 2 t's each)

__global__ __launch_bounds__(256) void general_pulling_kernel(
    const float* __restrict__ emb,    // [B,128] f32
    const float* __restrict__ refe,   // [B,128] f32
    const int*   __restrict__ anc_idx,
    const int*   __restrict__ pos_idx,
    const int*   __restrict__ neg_idx,
    const float* __restrict__ edge,   // [B,B,128] f32
    const float* __restrict__ javg_p, // [1] f32
    float*       __restrict__ out,    // [T,128] f32
    int T, int B)
{
    const int tid = threadIdx.x;
    const int g   = tid >> 5;     // group within block (0..7)
    const int sub = tid & 31;     // lane within 32-lane group
    const int t0  = blockIdx.x * TPB + g;
    const int t1  = t0 + 8;
    if (t0 >= T) return;
    const bool has1 = (t1 < T);

    const int anc0 = anc_idx[t0], pos0 = pos_idx[t0], neg0 = neg_idx[t0];
    const int tl   = has1 ? t1 : t0;
    const int anc1 = anc_idx[tl], pos1 = pos_idx[tl], neg1 = neg_idx[tl];

    // Streaming edge gathers: nontemporal, issued first (2x MLP).
    const float4_t le0 = __builtin_nontemporal_load(
        (const float4_t*)(edge + ((size_t)anc0 * B + neg0) * NB + sub * 4));
    const float4_t le1 = __builtin_nontemporal_load(
        (const float4_t*)(edge + ((size_t)anc1 * B + neg1) * NB + sub * 4));

    // L2-resident table reads (1 MB total) — keep cached.
    const float4_t ea0 = *(const float4_t*)(emb  + (size_t)anc0 * NB + sub * 4);
    const float4_t rp0 = *(const float4_t*)(refe + (size_t)pos0 * NB + sub * 4);
    const float4_t rn0 = *(const float4_t*)(refe + (size_t)neg0 * NB + sub * 4);
    const float4_t ea1 = *(const float4_t*)(emb  + (size_t)anc1 * NB + sub * 4);
    const float4_t rp1 = *(const float4_t*)(refe + (size_t)pos1 * NB + sub * 4);
    const float4_t rn1 = *(const float4_t*)(refe + (size_t)neg1 * NB + sub * 4);

    // scale = exp(-ALPHA/x), x = (J_avg==0 ? 1e6 : J_avg), ALPHA=1
    const float javg  = javg_p[0];
    const float x     = (javg == 0.0f) ? 1e6f : javg;
    const float scale = expf(-1.0f / x);

    float sap0 = 0.0f, san0 = 0.0f, sap1 = 0.0f, san1 = 0.0f;
    #pragma unroll
    for (int k = 0; k < 4; ++k) {
        float dp0 = ea0[k] - rp0[k], dn0 = ea0[k] - rn0[k];
        float dp1 = ea1[k] - rp1[k], dn1 = ea1[k] - rn1[k];
        sap0 += dp0 * dp0;  san0 += dn0 * dn0;
        sap1 += dp1 * dp1;  san1 += dn1 * dn1;
    }
    // butterfly reduce across the 32-lane group (32-aligned inside wave64)
    #pragma unroll
    for (int m = 1; m < 32; m <<= 1) {
        sap0 += __shfl_xor(sap0, m, 64);
        san0 += __shfl_xor(san0, m, 64);
        sap1 += __shfl_xor(sap1, m, 64);
        san1 += __shfl_xor(san1, m, 64);
    }

    const float D_ap0 = fmaxf(sqrtf(fmaxf(sap0, 0.0f)), 1e-6f);
    const float D_an0 = fmaxf(sqrtf(fmaxf(san0, 0.0f)), 1e-6f);
    const float D_ap1 = fmaxf(sqrtf(fmaxf(sap1, 0.0f)), 1e-6f);
    const float D_an1 = fmaxf(sqrtf(fmaxf(san1, 0.0f)), 1e-6f);
    const bool  negmask0 = (D_ap0 >= D_an0), negmask1 = (D_ap1 >= D_an1);
    const float ratio0   = D_ap0 / D_an0,    ratio1   = D_ap1 / D_an1;

    float4_t o0, o1;
    #pragma unroll
    for (int k = 0; k < 4; ++k) {
        const float lam0 = le0[k] * scale;
        const float r0   = ratio0 + lam0 * (1.0f - ratio0);
        const float z0   = ea0[k] + r0 * (rn0[k] - ea0[k]);
        o0[k] = negmask0 ? rn0[k] : z0;

        const float lam1 = le1[k] * scale;
        const float r1   = ratio1 + lam1 * (1.0f - ratio1);
        const float z1   = ea1[k] + r1 * (rn1[k] - ea1[k]);
        o1[k] = negmask1 ? rn1[k] : z1;
    }
    __builtin_nontemporal_store(o0, (float4_t*)(out + (size_t)t0 * NB + sub * 4));
    if (has1)
        __builtin_nontemporal_store(o1, (float4_t*)(out + (size_t)t1 * NB + sub * 4));
}

extern "C" void kernel_launch(void* const* d_in, const int* in_sizes, int n_in,
                              void* d_out, int out_size, void* d_ws, size_t ws_size,
                              hipStream_t stream) {
    const float* emb  = (const float*)d_in[0];
    const float* refe = (const float*)d_in[1];
    const int*   anc  = (const int*)d_in[2];
    const int*   pos  = (const int*)d_in[3];
    const int*   neg  = (const int*)d_in[4];
    const float* edge = (const float*)d_in[5];
    const float* javg = (const float*)d_in[6];
    float*       out  = (float*)d_out;

    const int T = in_sizes[2];           // 262144
    const int B = in_sizes[0] / NB;      // 1024

    const int blocks = (T + TPB - 1) / TPB;
    general_pulling_kernel<<<blocks, 256, 0, stream>>>(
        emb, refe, anc, pos, neg, edge, javg, out, T, B);
}

// Round 6
// 46.166 us; speedup vs baseline: 1.5073x; 1.4621x over previous
//
#include <hip/hip_runtime.h>

// GeneralPulling (all f32), fused (round-3 structure):
//   D_ap = ||emb[anc]-ref[pos]||, D_an = ||emb[anc]-ref[neg]||  (clip >= 1e-6)
//   lam_eta = edge[anc,neg,:] * exp(-1/J_avg)   (J_avg==0 -> x=1e6)
//   r = (1-lam_eta)*(D_ap/D_an) + lam_eta
//   z_hat = (D_ap >= D_an) ? ref[neg] : (1-r)*emb[anc] + r*ref[neg]
//
// 32 lanes per t, one float4 per lane -> 512 B coalesced row accesses.
// 2 t's per thread. Edge gathers CACHED (L3 captures ~16% dup reuse);
// output store NONTEMPORAL (single-use stream, don't evict edge lines).

typedef __attribute__((ext_vector_type(4))) float float4_t;

#define NB  128   // NBITS
#define TPB 16    // t's per block (8 groups x 2 t's each)

__global__ __launch_bounds__(256) void general_pulling_kernel(
    const float* __restrict__ emb,    // [B,128] f32
    const float* __restrict__ refe,   // [B,128] f32
    const int*   __restrict__ anc_idx,
    const int*   __restrict__ pos_idx,
    const int*   __restrict__ neg_idx,
    const float* __restrict__ edge,   // [B,B,128] f32
    const float* __restrict__ javg_p, // [1] f32
    float*       __restrict__ out,    // [T,128] f32
    int T, int B)
{
    const int tid = threadIdx.x;
    const int g   = tid >> 5;     // group within block (0..7)
    const int sub = tid & 31;     // lane within 32-lane group
    const int t0  = blockIdx.x * TPB + g;
    const int t1  = t0 + 8;
    if (t0 >= T) return;
    const bool has1 = (t1 < T);

    const int anc0 = anc_idx[t0], pos0 = pos_idx[t0], neg0 = neg_idx[t0];
    const int tl   = has1 ? t1 : t0;
    const int anc1 = anc_idx[tl], pos1 = pos_idx[tl], neg1 = neg_idx[tl];

    // Streaming edge gathers: cached (L3 reuse), issued first (2x MLP).
    const float4_t le0 = *(const float4_t*)(edge + ((size_t)anc0 * B + neg0) * NB + sub * 4);
    const float4_t le1 = *(const float4_t*)(edge + ((size_t)anc1 * B + neg1) * NB + sub * 4);

    // L2-resident table reads (1 MB total).
    const float4_t ea0 = *(const float4_t*)(emb  + (size_t)anc0 * NB + sub * 4);
    const float4_t rp0 = *(const float4_t*)(refe + (size_t)pos0 * NB + sub * 4);
    const float4_t rn0 = *(const float4_t*)(refe + (size_t)neg0 * NB + sub * 4);
    const float4_t ea1 = *(const float4_t*)(emb  + (size_t)anc1 * NB + sub * 4);
    const float4_t rp1 = *(const float4_t*)(refe + (size_t)pos1 * NB + sub * 4);
    const float4_t rn1 = *(const float4_t*)(refe + (size_t)neg1 * NB + sub * 4);

    // scale = exp(-ALPHA/x), x = (J_avg==0 ? 1e6 : J_avg), ALPHA=1
    const float javg  = javg_p[0];
    const float x     = (javg == 0.0f) ? 1e6f : javg;
    const float scale = expf(-1.0f / x);

    float sap0 = 0.0f, san0 = 0.0f, sap1 = 0.0f, san1 = 0.0f;
    #pragma unroll
    for (int k = 0; k < 4; ++k) {
        float dp0 = ea0[k] - rp0[k], dn0 = ea0[k] - rn0[k];
        float dp1 = ea1[k] - rp1[k], dn1 = ea1[k] - rn1[k];
        sap0 += dp0 * dp0;  san0 += dn0 * dn0;
        sap1 += dp1 * dp1;  san1 += dn1 * dn1;
    }
    // butterfly reduce across the 32-lane group (32-aligned inside wave64)
    #pragma unroll
    for (int m = 1; m < 32; m <<= 1) {
        sap0 += __shfl_xor(sap0, m, 64);
        san0 += __shfl_xor(san0, m, 64);
        sap1 += __shfl_xor(sap1, m, 64);
        san1 += __shfl_xor(san1, m, 64);
    }

    const float D_ap0 = fmaxf(sqrtf(fmaxf(sap0, 0.0f)), 1e-6f);
    const float D_an0 = fmaxf(sqrtf(fmaxf(san0, 0.0f)), 1e-6f);
    const float D_ap1 = fmaxf(sqrtf(fmaxf(sap1, 0.0f)), 1e-6f);
    const float D_an1 = fmaxf(sqrtf(fmaxf(san1, 0.0f)), 1e-6f);
    const bool  negmask0 = (D_ap0 >= D_an0), negmask1 = (D_ap1 >= D_an1);
    const float ratio0   = D_ap0 / D_an0,    ratio1   = D_ap1 / D_an1;

    float4_t o0, o1;
    #pragma unroll
    for (int k = 0; k < 4; ++k) {
        const float lam0 = le0[k] * scale;
        const float r0   = ratio0 + lam0 * (1.0f - ratio0);
        const float z0   = ea0[k] + r0 * (rn0[k] - ea0[k]);
        o0[k] = negmask0 ? rn0[k] : z0;

        const float lam1 = le1[k] * scale;
        const float r1   = ratio1 + lam1 * (1.0f - ratio1);
        const float z1   = ea1[k] + r1 * (rn1[k] - ea1[k]);
        o1[k] = negmask1 ? rn1[k] : z1;
    }
    __builtin_nontemporal_store(o0, (float4_t*)(out + (size_t)t0 * NB + sub * 4));
    if (has1)
        __builtin_nontemporal_store(o1, (float4_t*)(out + (size_t)t1 * NB + sub * 4));
}

extern "C" void kernel_launch(void* const* d_in, const int* in_sizes, int n_in,
                              void* d_out, int out_size, void* d_ws, size_t ws_size,
                              hipStream_t stream) {
    const float* emb  = (const float*)d_in[0];
    const float* refe = (const float*)d_in[1];
    const int*   anc  = (const int*)d_in[2];
    const int*   pos  = (const int*)d_in[3];
    const int*   neg  = (const int*)d_in[4];
    const float* edge = (const float*)d_in[5];
    const float* javg = (const float*)d_in[6];
    float*       out  = (float*)d_out;

    const int T = in_sizes[2];           // 262144
    const int B = in_sizes[0] / NB;      // 1024

    const int blocks = (T + TPB - 1) / TPB;
    general_pulling_kernel<<<blocks, 256, 0, stream>>>(
        emb, refe, anc, pos, neg, edge, javg, out, T, B);
}